// Round 1
// baseline (527.153 us; speedup 1.0000x reference)
//
#include <hip/hip_runtime.h>
#include <math.h>

#define HW   512
#define IMG  (512 * 512)
#define NB   64
// groups of 4 pixels along x: 512/4 = 128 per row
#define GROUPS_PER_ROW 128
#define TOTAL_GROUPS   (NB * HW * GROUPS_PER_ROW)   // 4,194,304
#define BLOCK 256

__global__ void eik_init_ws(float* ws) {
    ws[0] = 0.0f;   // violation sum
    ws[1] = 0.0f;   // mask count
}

__global__ __launch_bounds__(BLOCK) void eik_main(const float* __restrict__ pred,
                                                  const float* __restrict__ reach,
                                                  float* __restrict__ ws) {
    const int g = blockIdx.x * BLOCK + threadIdx.x;   // group id, one per 4 pixels
    const int x0 = (g & (GROUPS_PER_ROW - 1)) << 2;   // 0..508, multiple of 4
    const int y  = (g >> 7) & (HW - 1);
    const int b  = g >> 16;

    const float* base = pred + (size_t)b * IMG;
    const float* row0 = base + (size_t)y * HW;
    const float* rowm = base + (size_t)(y > 0      ? y - 1 : 0)      * HW;
    const float* rowp = base + (size_t)(y < HW - 1 ? y + 1 : HW - 1) * HW;

    const float4 cm = *(const float4*)(rowm + x0);
    const float4 c0 = *(const float4*)(row0 + x0);
    const float4 cp = *(const float4*)(rowp + x0);
    // edge-replicate halo in x
    const float lm = (x0 == 0)        ? rowm[0]   : rowm[x0 - 1];
    const float l0 = (x0 == 0)        ? row0[0]   : row0[x0 - 1];
    const float lp = (x0 == 0)        ? rowp[0]   : rowp[x0 - 1];
    const float rm = (x0 == HW - 4)   ? rowm[HW-1] : rowm[x0 + 4];
    const float r0 = (x0 == HW - 4)   ? row0[HW-1] : row0[x0 + 4];
    const float rp = (x0 == HW - 4)   ? rowp[HW-1] : rowp[x0 + 4];

    const float wm[6] = {lm, cm.x, cm.y, cm.z, cm.w, rm};
    const float w0[6] = {l0, c0.x, c0.y, c0.z, c0.w, r0};
    const float wp[6] = {lp, cp.x, cp.y, cp.z, cp.w, rp};

    const float4 rch = *(const float4*)(reach + (size_t)b * IMG + (size_t)y * HW + x0);
    const float rv[4] = {rch.x, rch.y, rch.z, rch.w};

    float vsum = 0.0f;
    float csum = 0.0f;
#pragma unroll
    for (int i = 0; i < 4; ++i) {
        // cross-correlation with Sobel/8, edge-replicated
        const float gx = ((wm[i+2] - wm[i]) + 2.0f * (w0[i+2] - w0[i]) + (wp[i+2] - wp[i])) * 0.125f;
        const float gy = ((wp[i]   - wm[i]) + 2.0f * (wp[i+1] - wm[i+1]) + (wp[i+2] - wm[i+2])) * 0.125f;
        const float mag  = sqrtf(gx * gx + gy * gy + 1e-8f);
        const float viol = fabsf(mag - 1.0f);
        const bool  m    = rv[i] > 0.5f;
        vsum += m ? viol : 0.0f;
        csum += m ? 1.0f : 0.0f;
    }

    // wave-64 butterfly reduction
#pragma unroll
    for (int off = 32; off > 0; off >>= 1) {
        vsum += __shfl_down(vsum, off, 64);
        csum += __shfl_down(csum, off, 64);
    }

    __shared__ float sv[BLOCK / 64];
    __shared__ float sc[BLOCK / 64];
    const int lane = threadIdx.x & 63;
    const int wid  = threadIdx.x >> 6;
    if (lane == 0) { sv[wid] = vsum; sc[wid] = csum; }
    __syncthreads();
    if (threadIdx.x == 0) {
        float v = sv[0] + sv[1] + sv[2] + sv[3];
        float c = sc[0] + sc[1] + sc[2] + sc[3];
        atomicAdd(&ws[0], v);
        atomicAdd(&ws[1], c);
    }
}

__global__ void eik_finalize(const float* __restrict__ ws, float* __restrict__ out) {
    out[0] = ws[0] / fmaxf(ws[1], 1.0f);
}

extern "C" void kernel_launch(void* const* d_in, const int* in_sizes, int n_in,
                              void* d_out, int out_size, void* d_ws, size_t ws_size,
                              hipStream_t stream) {
    const float* pred  = (const float*)d_in[0];
    const float* reach = (const float*)d_in[1];
    float* out = (float*)d_out;
    float* ws  = (float*)d_ws;

    eik_init_ws<<<1, 1, 0, stream>>>(ws);
    eik_main<<<TOTAL_GROUPS / BLOCK, BLOCK, 0, stream>>>(pred, reach, ws);
    eik_finalize<<<1, 1, 0, stream>>>(ws, out);
}

// Round 2
// 150.626 us; speedup vs baseline: 3.4997x; 3.4997x over previous
//
#include <hip/hip_runtime.h>
#include <math.h>

#define HW   512
#define IMG  (512 * 512)
#define NB   64
// groups of 4 pixels along x: 512/4 = 128 per row
#define GROUPS_PER_ROW 128
#define TOTAL_GROUPS   (NB * HW * GROUPS_PER_ROW)   // 4,194,304
#define BLOCK 256
#define NBLOCKS 2048                                 // 8 blocks/CU on 256 CUs
#define NTHREADS (NBLOCKS * BLOCK)                   // 524,288 -> 8 groups/thread

__global__ __launch_bounds__(BLOCK) void eik_main(const float* __restrict__ pred,
                                                  const float* __restrict__ reach,
                                                  float* __restrict__ partials) {
    float vsum = 0.0f;
    float csum = 0.0f;

    for (int g = blockIdx.x * BLOCK + threadIdx.x; g < TOTAL_GROUPS; g += NTHREADS) {
        const int x0 = (g & (GROUPS_PER_ROW - 1)) << 2;   // 0..508, multiple of 4
        const int y  = (g >> 7) & (HW - 1);
        const int b  = g >> 16;

        const float* base = pred + (size_t)b * IMG;
        const float* row0 = base + (size_t)y * HW;
        const float* rowm = base + (size_t)(y > 0      ? y - 1 : 0)      * HW;
        const float* rowp = base + (size_t)(y < HW - 1 ? y + 1 : HW - 1) * HW;

        const float4 cm = *(const float4*)(rowm + x0);
        const float4 c0 = *(const float4*)(row0 + x0);
        const float4 cp = *(const float4*)(rowp + x0);
        // edge-replicate halo in x
        const float lm = (x0 == 0)        ? rowm[0]    : rowm[x0 - 1];
        const float l0 = (x0 == 0)        ? row0[0]    : row0[x0 - 1];
        const float lp = (x0 == 0)        ? rowp[0]    : rowp[x0 - 1];
        const float rm = (x0 == HW - 4)   ? rowm[HW-1] : rowm[x0 + 4];
        const float r0 = (x0 == HW - 4)   ? row0[HW-1] : row0[x0 + 4];
        const float rp = (x0 == HW - 4)   ? rowp[HW-1] : rowp[x0 + 4];

        const float wm[6] = {lm, cm.x, cm.y, cm.z, cm.w, rm};
        const float w0[6] = {l0, c0.x, c0.y, c0.z, c0.w, r0};
        const float wp[6] = {lp, cp.x, cp.y, cp.z, cp.w, rp};

        const float4 rch = *(const float4*)(reach + (size_t)b * IMG + (size_t)y * HW + x0);
        const float rv[4] = {rch.x, rch.y, rch.z, rch.w};

#pragma unroll
        for (int i = 0; i < 4; ++i) {
            const float gx = ((wm[i+2] - wm[i]) + 2.0f * (w0[i+2] - w0[i]) + (wp[i+2] - wp[i])) * 0.125f;
            const float gy = ((wp[i]   - wm[i]) + 2.0f * (wp[i+1] - wm[i+1]) + (wp[i+2] - wm[i+2])) * 0.125f;
            const float mag  = sqrtf(gx * gx + gy * gy + 1e-8f);
            const float viol = fabsf(mag - 1.0f);
            const bool  m    = rv[i] > 0.5f;
            vsum += m ? viol : 0.0f;
            csum += m ? 1.0f : 0.0f;
        }
    }

    // wave-64 butterfly reduction
#pragma unroll
    for (int off = 32; off > 0; off >>= 1) {
        vsum += __shfl_down(vsum, off, 64);
        csum += __shfl_down(csum, off, 64);
    }

    __shared__ float sv[BLOCK / 64];
    __shared__ float sc[BLOCK / 64];
    const int lane = threadIdx.x & 63;
    const int wid  = threadIdx.x >> 6;
    if (lane == 0) { sv[wid] = vsum; sc[wid] = csum; }
    __syncthreads();
    if (threadIdx.x == 0) {
        partials[2 * blockIdx.x]     = sv[0] + sv[1] + sv[2] + sv[3];
        partials[2 * blockIdx.x + 1] = sc[0] + sc[1] + sc[2] + sc[3];
    }
}

__global__ __launch_bounds__(BLOCK) void eik_finalize(const float* __restrict__ partials,
                                                      float* __restrict__ out) {
    float v = 0.0f, c = 0.0f;
    for (int i = threadIdx.x; i < NBLOCKS; i += BLOCK) {
        v += partials[2 * i];
        c += partials[2 * i + 1];
    }
#pragma unroll
    for (int off = 32; off > 0; off >>= 1) {
        v += __shfl_down(v, off, 64);
        c += __shfl_down(c, off, 64);
    }
    __shared__ float sv[BLOCK / 64];
    __shared__ float sc[BLOCK / 64];
    const int lane = threadIdx.x & 63;
    const int wid  = threadIdx.x >> 6;
    if (lane == 0) { sv[wid] = v; sc[wid] = c; }
    __syncthreads();
    if (threadIdx.x == 0) {
        const float vt = sv[0] + sv[1] + sv[2] + sv[3];
        const float ct = sc[0] + sc[1] + sc[2] + sc[3];
        out[0] = vt / fmaxf(ct, 1.0f);
    }
}

extern "C" void kernel_launch(void* const* d_in, const int* in_sizes, int n_in,
                              void* d_out, int out_size, void* d_ws, size_t ws_size,
                              hipStream_t stream) {
    const float* pred  = (const float*)d_in[0];
    const float* reach = (const float*)d_in[1];
    float* out = (float*)d_out;
    float* ws  = (float*)d_ws;

    eik_main<<<NBLOCKS, BLOCK, 0, stream>>>(pred, reach, ws);
    eik_finalize<<<1, BLOCK, 0, stream>>>(ws, out);
}

// Round 3
// 148.097 us; speedup vs baseline: 3.5595x; 1.0171x over previous
//
#include <hip/hip_runtime.h>
#include <math.h>

#define HW   512
#define IMG  (512 * 512)
#define NB   64
#define T    8                    // rows marched per wave
#define BLOCK 256
#define WAVES_PER_IMG (HW / T)    // 64
#define TOTAL_WAVES   (NB * WAVES_PER_IMG)          // 4096
#define NBLOCKS       (TOTAL_WAVES / (BLOCK / 64))  // 1024

__device__ __forceinline__ void load_row(const float* __restrict__ prow, int r, int lane,
                                         float4& q0, float4& q1) {
    const float* p = prow + (size_t)r * HW + (lane << 3);
    q0 = *(const float4*)p;
    q1 = *(const float4*)(p + 4);
}

__device__ __forceinline__ void make_window(const float4& q0, const float4& q1, int lane,
                                            float* w) {
    float lft = __shfl_up(q1.w, 1, 64);    // lane-1's last element = row[x_start-1]
    float rgt = __shfl_down(q0.x, 1, 64);  // lane+1's first element = row[x_start+8]
    if (lane == 0)  lft = q0.x;            // edge replicate row[0]
    if (lane == 63) rgt = q1.w;            // edge replicate row[511]
    w[0] = lft;  w[1] = q0.x; w[2] = q0.y; w[3] = q0.z; w[4] = q0.w;
    w[5] = q1.x; w[6] = q1.y; w[7] = q1.z; w[8] = q1.w; w[9] = rgt;
}

__global__ __launch_bounds__(BLOCK) void eik_main(const float* __restrict__ pred,
                                                  const float* __restrict__ reach,
                                                  float* __restrict__ partials) {
    const int lane = threadIdx.x & 63;
    const int wave = blockIdx.x * (BLOCK / 64) + (threadIdx.x >> 6);
    const int b    = wave >> 6;               // image index (64 waves per image)
    const int y0   = (wave & (WAVES_PER_IMG - 1)) * T;

    const float* prow = pred  + (size_t)b * IMG;
    const float* rrow = reach + (size_t)b * IMG;

    float wm[10], w0[10], wp[10];
    float4 a0, a1;
    load_row(prow, (y0 > 0 ? y0 - 1 : 0), lane, a0, a1);
    make_window(a0, a1, lane, wm);
    load_row(prow, y0, lane, a0, a1);
    make_window(a0, a1, lane, w0);

    float vsum = 0.0f, csum = 0.0f;

#pragma unroll
    for (int t = 0; t < T; ++t) {
        const int y  = y0 + t;
        const int yp = (y + 1 < HW) ? y + 1 : HW - 1;
        load_row(prow, yp, lane, a0, a1);

        const float* rp = rrow + (size_t)y * HW + (lane << 3);
        const float4 r0 = *(const float4*)rp;
        const float4 r1 = *(const float4*)(rp + 4);

        make_window(a0, a1, lane, wp);

        const float rv[8] = {r0.x, r0.y, r0.z, r0.w, r1.x, r1.y, r1.z, r1.w};
#pragma unroll
        for (int i = 0; i < 8; ++i) {
            const float gx = ((wm[i+2] - wm[i]) + 2.0f * (w0[i+2] - w0[i]) + (wp[i+2] - wp[i])) * 0.125f;
            const float gy = ((wp[i]   - wm[i]) + 2.0f * (wp[i+1] - wm[i+1]) + (wp[i+2] - wm[i+2])) * 0.125f;
            const float mag  = sqrtf(gx * gx + gy * gy + 1e-8f);
            const float viol = fabsf(mag - 1.0f);
            const bool  m    = rv[i] > 0.5f;
            vsum += m ? viol : 0.0f;
            csum += m ? 1.0f : 0.0f;
        }
        // rotate window: wm <- w0 <- wp (register renaming after full unroll)
#pragma unroll
        for (int i = 0; i < 10; ++i) { wm[i] = w0[i]; w0[i] = wp[i]; }
    }

    // wave-64 reduction
#pragma unroll
    for (int off = 32; off > 0; off >>= 1) {
        vsum += __shfl_down(vsum, off, 64);
        csum += __shfl_down(csum, off, 64);
    }

    __shared__ float sv[BLOCK / 64];
    __shared__ float sc[BLOCK / 64];
    const int wid = threadIdx.x >> 6;
    if (lane == 0) { sv[wid] = vsum; sc[wid] = csum; }
    __syncthreads();
    if (threadIdx.x == 0) {
        partials[2 * blockIdx.x]     = sv[0] + sv[1] + sv[2] + sv[3];
        partials[2 * blockIdx.x + 1] = sc[0] + sc[1] + sc[2] + sc[3];
    }
}

__global__ __launch_bounds__(BLOCK) void eik_finalize(const float* __restrict__ partials,
                                                      float* __restrict__ out) {
    float v = 0.0f, c = 0.0f;
    for (int i = threadIdx.x; i < NBLOCKS; i += BLOCK) {
        v += partials[2 * i];
        c += partials[2 * i + 1];
    }
#pragma unroll
    for (int off = 32; off > 0; off >>= 1) {
        v += __shfl_down(v, off, 64);
        c += __shfl_down(c, off, 64);
    }
    __shared__ float sv[BLOCK / 64];
    __shared__ float sc[BLOCK / 64];
    const int lane = threadIdx.x & 63;
    const int wid  = threadIdx.x >> 6;
    if (lane == 0) { sv[wid] = v; sc[wid] = c; }
    __syncthreads();
    if (threadIdx.x == 0) {
        const float vt = sv[0] + sv[1] + sv[2] + sv[3];
        const float ct = sc[0] + sc[1] + sc[2] + sc[3];
        out[0] = vt / fmaxf(ct, 1.0f);
    }
}

extern "C" void kernel_launch(void* const* d_in, const int* in_sizes, int n_in,
                              void* d_out, int out_size, void* d_ws, size_t ws_size,
                              hipStream_t stream) {
    const float* pred  = (const float*)d_in[0];
    const float* reach = (const float*)d_in[1];
    float* out = (float*)d_out;
    float* ws  = (float*)d_ws;

    eik_main<<<NBLOCKS, BLOCK, 0, stream>>>(pred, reach, ws);
    eik_finalize<<<1, BLOCK, 0, stream>>>(ws, out);
}